// Round 22
// baseline (127.256 us; speedup 1.0000x reference)
//
#include <hip/hip_runtime.h>
#include <hip/hip_bf16.h>

#define B_   2
#define T_   2048
#define D_   1024
#define H_   16
#define HD_  64
#define M_TOT (B_*T_)    // 4096
#define N_QKV (3*D_)     // 3072

typedef __attribute__((ext_vector_type(8))) short bf16x8;
typedef __attribute__((ext_vector_type(4))) float f32x4;
typedef __attribute__((ext_vector_type(16))) float f32x16;

static __device__ __forceinline__ short f2bf(float f) {
    union { __hip_bfloat16 h; short s; } u;
    u.h = __float2bfloat16(f);
    return u.s;
}
static __device__ __forceinline__ unsigned pack2(float a, float b) {
    return (unsigned)(unsigned short)f2bf(a) | ((unsigned)(unsigned short)f2bf(b) << 16);
}
// HW packed f32->bf16 (RNE): D.lo16 = bf16(lo), D.hi16 = bf16(hi). 1 VALU op
// vs ~10 for the software pack2 (T12's cvt_pk half; m214 v22).
static __device__ __forceinline__ unsigned cvtpk(float lo, float hi) {
    unsigned r;
    asm("v_cvt_pk_bf16_f32 %0, %1, %2" : "=v"(r) : "v"(lo), "v"(hi));
    return r;
}
static __device__ __forceinline__ float exp2_fast(float x) {
    return __builtin_amdgcn_exp2f(x);
}
static __device__ __forceinline__ f32x16 zero16() {
    f32x16 z;
    #pragma unroll
    for (int i = 0; i < 16; ++i) z[i] = 0.f;
    return z;
}
// async global->LDS DMA, 16B per lane. LDS dest = wave-uniform base + lane*16.
static __device__ __forceinline__ void gload16(const void* g, void* l) {
    __builtin_amdgcn_global_load_lds(
        (__attribute__((address_space(1))) unsigned int*)(unsigned long long)g,
        (__attribute__((address_space(3))) unsigned int*)l, 16, 0, 0);
}
// NOTE (R9-R12): v_permlane32_swap_b32 failed the 2x2 factorial; PV exchange
// stays on __shfl_xor (verified). NOTE (R14): counted-vmcnt in attn neutral.
// NOTE (R16): T15 att[2] pipeline regressed (VGPR 2x). NOTE (R17): depth-2
// GEMM prefetch neutral (kept). NOTE (R18/R19): KV split-K dispatch win eaten
// by combine overhead -- reverted. NOTE (R20): bh-grouped grid cut attn FETCH
// 69.7->12.3MB (kept). NOTE (R21): HW cvt_pk P-pack -3us (kept).
// R22: T5 s_setprio(1) around attn's QK/PV MFMA clusters (m191: attn +4-7%;
// waves drift between per-tile barriers -> scheduler has roles to arbitrate).

// ---------------------------------------------------------------------------
// x fp32 -> bf16, straight copy (8 elems/thread)
__global__ __launch_bounds__(256) void convert_x(const float* __restrict__ x,
                                                 short* __restrict__ xb, int n8) {
    int i = blockIdx.x * blockDim.x + threadIdx.x;
    if (i >= n8) return;
    const float4* p = (const float4*)x + (size_t)i * 2;
    float4 a = p[0], b = p[1];
    bf16x8 o;
    o[0]=f2bf(a.x); o[1]=f2bf(a.y); o[2]=f2bf(a.z); o[3]=f2bf(a.w);
    o[4]=f2bf(b.x); o[5]=f2bf(b.y); o[6]=f2bf(b.z); o[7]=f2bf(b.w);
    *((bf16x8*)xb + i) = o;
}

// in [K][N] fp32  ->  out [N][K] bf16 (B^T layout for GEMM), 64x64 LDS tiles
__global__ __launch_bounds__(256) void transpose_convert(const float* __restrict__ in,
                                                         short* __restrict__ out,
                                                         int K, int N) {
    __shared__ short tile[64][65];
    int k0 = blockIdx.y * 64, n0 = blockIdx.x * 64;
    int t = threadIdx.x;
    #pragma unroll
    for (int i = 0; i < 16; ++i) {
        int idx = i * 256 + t;
        int r = idx >> 6, c = idx & 63;
        tile[r][c] = f2bf(in[(size_t)(k0 + r) * N + n0 + c]);
    }
    __syncthreads();
    #pragma unroll
    for (int i = 0; i < 16; ++i) {
        int idx = i * 256 + t;
        int r = idx >> 6, c = idx & 63;     // r: n-local, c: k-local
        out[(size_t)(n0 + r) * K + k0 + c] = tile[c][r];
    }
}

// ---------------------------------------------------------------------------
// BK=32 GEMM with depth-2 prefetch (R17-verified). C = A*BT^T + bias.
#define QSC 0.18033688f   // 0.125 * log2(e)
template<int BM, int BN, int MODE>
__global__ __launch_bounds__(256)
void gemm_dl(const short* __restrict__ A, const short* __restrict__ BT,
             const float* __restrict__ bias, int M, int N, int K,
             short* __restrict__ qo, short* __restrict__ ko,
             short* __restrict__ vo, float* __restrict__ fo) {
    constexpr int BUF = (BM + BN) * 64;        // bytes per stage buffer (64B rows)
    constexpr int NL = (BM + BN) / 64;         // DMA instrs per thread per stage
    __shared__ char smem[3 * BUF];
    const int t = threadIdx.x, w = t >> 6, l = t & 63;
    const int qi_l = l & 15, hi_l = l >> 4;
    const int m0 = blockIdx.y * BM, n0 = blockIdx.x * BN;
    const int wr = w >> 1, wc = w & 1;
    constexpr int MI = BM / 32, NI = BN / 32;

    f32x4 acc[MI][NI];
    #pragma unroll
    for (int mi = 0; mi < MI; ++mi)
        #pragma unroll
        for (int ni = 0; ni < NI; ++ni)
            acc[mi][ni] = (f32x4){0.f, 0.f, 0.f, 0.f};

    const int lrow = l >> 2;                     // 0..15 rows within one 1KB DMA
    const int lch  = ((l & 3) ^ (lrow & 3)) * 8; // pre-swizzled source chunk (elems)

    auto stage = [&](char* dst, int k0) {
        #pragma unroll
        for (int i = 0; i < BM / 64; ++i) {
            int rb = w * (BM / 4) + i * 16;
            gload16(A + (size_t)(m0 + rb + lrow) * K + k0 + lch, dst + rb * 64);
        }
        #pragma unroll
        for (int i = 0; i < BN / 64; ++i) {
            int rb = w * (BN / 4) + i * 16;
            gload16(BT + (size_t)(n0 + rb + lrow) * K + k0 + lch, dst + BM * 64 + rb * 64);
        }
    };

    const int nt = K / 32;
    stage(smem, 0);
    if (nt > 1) stage(smem + BUF, 32);
    for (int it = 0; it < nt; ++it) {
        if (it + 2 < nt) {
            stage(smem + ((it + 2) % 3) * BUF, (it + 2) * 32);  // t+2 in flight
            if constexpr (NL == 4)      asm volatile("s_waitcnt vmcnt(8)" ::: "memory");
            else if constexpr (NL == 3) asm volatile("s_waitcnt vmcnt(6)" ::: "memory");
            else                        asm volatile("s_waitcnt vmcnt(0)" ::: "memory");
        } else if (it + 1 < nt) {
            if constexpr (NL == 4)      asm volatile("s_waitcnt vmcnt(4)" ::: "memory");
            else if constexpr (NL == 3) asm volatile("s_waitcnt vmcnt(3)" ::: "memory");
            else                        asm volatile("s_waitcnt vmcnt(0)" ::: "memory");
        } else {
            asm volatile("s_waitcnt vmcnt(0)" ::: "memory");
        }
        __builtin_amdgcn_s_barrier();    // B1: tile t visible to all waves

        char* sA = smem + (it % 3) * BUF;
        char* sB = sA + BM * 64;
        bf16x8 af[MI], bfr[NI];
        #pragma unroll
        for (int mi = 0; mi < MI; ++mi) {
            int row = wr * (BM / 2) + mi * 16 + qi_l;
            int ad = row * 64 + ((hi_l ^ (row & 3)) * 16);
            af[mi] = *(const bf16x8*)(sA + ad);
        }
        #pragma unroll
        for (int ni = 0; ni < NI; ++ni) {
            int row = wc * (BN / 2) + ni * 16 + qi_l;
            int ad = row * 64 + ((hi_l ^ (row & 3)) * 16);
            bfr[ni] = *(const bf16x8*)(sB + ad);
        }
        #pragma unroll
        for (int mi = 0; mi < MI; ++mi)
            #pragma unroll
            for (int ni = 0; ni < NI; ++ni)
                acc[mi][ni] = __builtin_amdgcn_mfma_f32_16x16x32_bf16(af[mi], bfr[ni], acc[mi][ni], 0, 0, 0);

        __builtin_amdgcn_s_barrier();    // B2: buf[it%3] reads done
    }

    #pragma unroll
    for (int mi = 0; mi < MI; ++mi) {
        int rbase = m0 + wr * (BM / 2) + mi * 16 + 4 * hi_l;
        #pragma unroll
        for (int ni = 0; ni < NI; ++ni) {
            int n = n0 + wc * (BN / 2) + ni * 16 + qi_l;
            float bv = bias[n];
            #pragma unroll
            for (int r = 0; r < 4; ++r) {
                int mm = rbase + r;
                float c = acc[mi][ni][r] + bv;
                if (MODE == 0) {
                    int which = n >> 10, rest = n & 1023;
                    int h = rest >> 6, d = rest & 63;
                    int b = mm >> 11, tq = mm & 2047;
                    size_t bh = (size_t)(b * H_ + h);
                    if (which == 0)      qo[(bh * T_ + tq) * HD_ + d] = f2bf(c * QSC);
                    else if (which == 1) ko[(bh * T_ + tq) * HD_ + d] = f2bf(c);
                    else                 vo[(bh * HD_ + d) * T_ + tq] = f2bf(c);
                } else {
                    fo[(size_t)mm * N + n] = c;
                }
            }
        }
    }
}

// ---------------------------------------------------------------------------
// Flash attention (R21-verified structure: bh-major grid -> XCD=bh%8 L2
// locality; 8 waves x 32 q-rows, KVBLK=64, swapped 32x32 MFMA; HW cvt_pk).
// R22: s_setprio(1) around the QK and PV MFMA clusters (T5).
// q,k: [B*H, T, Hd] bf16 (q pre-scaled by 1/8*log2e); vt: [B*H, Hd, T] bf16.
__global__ __launch_bounds__(512)
void attn(const short* __restrict__ q, const short* __restrict__ k,
          const short* __restrict__ vt, short* __restrict__ ao) {
    __shared__ char smem[32768];   // buf0: K@0 V@8192; buf1: K@16384 V@24576

    const int t = threadIdx.x, w = t >> 6, l = t & 63;
    const int q32 = l & 31, hi2 = l >> 5;
    const int swz = (l & 7) << 4;
    const int bh = blockIdx.x;                     // bh on x: XCD = bh % 8
    const int q0 = blockIdx.y * 256 + w * 32;      // q-tile on y

    const short* qptr = q + ((size_t)bh * T_ + q0) * HD_;
    const short* kbase = k + (size_t)bh * T_ * HD_;
    const short* vbase = vt + (size_t)bh * HD_ * T_;

    const int srow = w * 8 + (l >> 3);              // staging row (this wave: 8 rows)
    const int sch  = ((l & 7) ^ (l >> 3)) * 8;      // pre-swizzled source chunk

    // Q fragments: B-operand of 32x32x16: lane holds Q[q=q32][d = kc*16 + hi2*8 + j]
    bf16x8 qa[4];
    #pragma unroll
    for (int kc = 0; kc < 4; ++kc)
        qa[kc] = *(const bf16x8*)(qptr + q32 * HD_ + kc * 16 + hi2 * 8);

    f32x16 o0 = zero16(), o1 = zero16();
    float m = -1e30f, lsum = 0.f;

    // prologue: stage tile 0 into buf 0 (1 K + 1 V DMA per thread)
    gload16(kbase + (size_t)srow * HD_ + sch, smem + srow * 128);
    gload16(vbase + (size_t)srow * T_ + sch,  smem + 8192 + srow * 128);
    __syncthreads();

    int cur = 0;
    for (int kb = 0; kb < T_; kb += 64) {
        char* sK = smem + cur * 16384;
        char* sV = sK + 8192;
        if (kb + 64 < T_) {
            char* nK = smem + (cur ^ 1) * 16384;
            gload16(kbase + (size_t)(kb + 64 + srow) * HD_ + sch, nK + srow * 128);
            gload16(vbase + (size_t)srow * T_ + (kb + 64) + sch,  nK + 8192 + srow * 128);
        }

        // S^T: two 32x32 tiles (kvt=0,1), accumulate over Hd in 4 chunks of 16
        f32x16 s0 = zero16(), s1 = zero16();
        __builtin_amdgcn_s_setprio(1);
        #pragma unroll
        for (int kc = 0; kc < 4; ++kc) {
            int off = (kc * 32 + hi2 * 16) ^ swz;
            bf16x8 kf0 = *(const bf16x8*)(sK + q32 * 128 + off);
            s0 = __builtin_amdgcn_mfma_f32_32x32x16_bf16(kf0, qa[kc], s0, 0, 0, 0);
            bf16x8 kf1 = *(const bf16x8*)(sK + (32 + q32) * 128 + off);
            s1 = __builtin_amdgcn_mfma_f32_32x32x16_bf16(kf1, qa[kc], s1, 0, 0, 0);
        }
        __builtin_amdgcn_s_setprio(0);

        // row max: 32 in-lane (tree) + 1 exchange with lane^32
        float a8[8];
        #pragma unroll
        for (int i = 0; i < 8; ++i)
            a8[i] = fmaxf(fmaxf(s0[i], s0[i + 8]), fmaxf(s1[i], s1[i + 8]));
        float b4_0 = fmaxf(a8[0], a8[1]), b4_1 = fmaxf(a8[2], a8[3]);
        float b4_2 = fmaxf(a8[4], a8[5]), b4_3 = fmaxf(a8[6], a8[7]);
        float tm = fmaxf(fmaxf(b4_0, b4_1), fmaxf(b4_2, b4_3));
        tm = fmaxf(tm, __shfl_xor(tm, 32));

        // defer-max (T13): skip O-rescale when max growth <= 8 (log2 domain)
        if (!__all(tm <= m + 8.f)) {
            float mnew = fmaxf(m, tm);
            float fsc = exp2_fast(m - mnew);
            lsum *= fsc;
            #pragma unroll
            for (int i = 0; i < 16; ++i) { o0[i] *= fsc; o1[i] *= fsc; }
            m = mnew;
        }

        // P = exp2(S - m); row-sum (tree + 1 shfl); pack to bf16 pairs (HW cvt_pk)
        #pragma unroll
        for (int i = 0; i < 16; ++i) {
            s0[i] = exp2_fast(s0[i] - m);
            s1[i] = exp2_fast(s1[i] - m);
        }
        float p8[8];
        #pragma unroll
        for (int i = 0; i < 8; ++i)
            p8[i] = (s0[i] + s0[i + 8]) + (s1[i] + s1[i + 8]);
        float psum = ((p8[0] + p8[1]) + (p8[2] + p8[3])) + ((p8[4] + p8[5]) + (p8[6] + p8[7]));
        psum += __shfl_xor(psum, 32);
        lsum += psum;

        unsigned pk0[8], pk1[8];
        #pragma unroll
        for (int p = 0; p < 8; ++p) {
            pk0[p] = cvtpk(s0[2 * p], s0[2 * p + 1]);
            pk1[p] = cvtpk(s1[2 * p], s1[2 * p + 1]);
        }

        // PV: for each 16-kv chunk c, build P^T B-fragment in-register
        // (shfl_xor lane+-32 exchange -- VERIFIED mapping) and accumulate
        // O^T (two 32-row d-tiles) over the kv dimension.
        __builtin_amdgcn_s_setprio(1);
        #pragma unroll
        for (int c = 0; c < 4; ++c) {
            unsigned w0 = (c & 2) ? pk1[(c & 1) * 4 + 0] : pk0[(c & 1) * 4 + 0];
            unsigned w1 = (c & 2) ? pk1[(c & 1) * 4 + 1] : pk0[(c & 1) * 4 + 1];
            unsigned w2 = (c & 2) ? pk1[(c & 1) * 4 + 2] : pk0[(c & 1) * 4 + 2];
            unsigned w3 = (c & 2) ? pk1[(c & 1) * 4 + 3] : pk0[(c & 1) * 4 + 3];
            unsigned t0 = hi2 ? w0 : w2;
            unsigned t1 = hi2 ? w1 : w3;
            unsigned r0 = __shfl_xor(t0, 32);
            unsigned r1 = __shfl_xor(t1, 32);
            union { unsigned u[4]; bf16x8 v; } uf;
            uf.u[0] = hi2 ? r0 : w0;
            uf.u[1] = hi2 ? r1 : w1;
            uf.u[2] = hi2 ? w2 : r0;
            uf.u[3] = hi2 ? w3 : r1;
            bf16x8 pf = uf.v;

            int off = (c * 32 + hi2 * 16) ^ swz;
            bf16x8 vf0 = *(const bf16x8*)(sV + q32 * 128 + off);
            o0 = __builtin_amdgcn_mfma_f32_32x32x16_bf16(vf0, pf, o0, 0, 0, 0);
            bf16x8 vf1 = *(const bf16x8*)(sV + (32 + q32) * 128 + off);
            o1 = __builtin_amdgcn_mfma_f32_32x32x16_bf16(vf1, pf, o1, 0, 0, 0);
        }
        __builtin_amdgcn_s_setprio(0);

        __syncthreads();    // DMA drained + all waves done with buf[cur]
        cur ^= 1;
    }

    const float inv = 1.f / lsum;
    const int b = bh >> 4, h = bh & 15;
    const int tq = q0 + q32;
    unsigned* aou = (unsigned*)(ao + ((size_t)(b * T_ + tq)) * D_ + h * HD_);
    #pragma unroll
    for (int pr = 0; pr < 8; ++pr) {
        int d0 = 2 * (pr & 1) + 8 * (pr >> 1) + 4 * hi2;    // even
        aou[d0 >> 1]        = pack2(o0[2 * pr] * inv, o0[2 * pr + 1] * inv);
        aou[(32 + d0) >> 1] = pack2(o1[2 * pr] * inv, o1[2 * pr + 1] * inv);
    }
}

// ---------------------------------------------------------------------------
extern "C" void kernel_launch(void* const* d_in, const int* in_sizes, int n_in,
                              void* d_out, int out_size, void* d_ws, size_t ws_size,
                              hipStream_t stream) {
    const float* x    = (const float*)d_in[0];
    const float* Wqkv = (const float*)d_in[1];
    const float* bqkv = (const float*)d_in[2];
    const float* Wout = (const float*)d_in[3];
    const float* bout = (const float*)d_in[4];
    float* out = (float*)d_out;

    char* ws = (char*)d_ws;
    short* xb  = (short*)(ws);                      // 8 MB  x bf16 [4096][1024]
    short* WqT = (short*)(ws + ((size_t)8  << 20)); // 6 MB  Wqkv^T bf16 [3072][1024]
    short* WoT = (short*)(ws + ((size_t)14 << 20)); // 2 MB  Wout^T bf16 [1024][1024]
    short* qb  = (short*)(ws + ((size_t)16 << 20)); // 8 MB  q [B*H][T][Hd]
    short* kb  = (short*)(ws + ((size_t)24 << 20)); // 8 MB  k [B*H][T][Hd]
    short* vtb = (short*)(ws + ((size_t)32 << 20)); // 8 MB  v^T [B*H][Hd][T]
    short* aob = (short*)(ws + ((size_t)40 << 20)); // 8 MB  attn out bf16 [4096][1024]

    convert_x<<<(M_TOT * D_ / 8 + 255) / 256, 256, 0, stream>>>(x, xb, M_TOT * D_ / 8);
    transpose_convert<<<dim3(N_QKV / 64, D_ / 64), 256, 0, stream>>>(Wqkv, WqT, D_, N_QKV);
    transpose_convert<<<dim3(D_ / 64, D_ / 64), 256, 0, stream>>>(Wout, WoT, D_, D_);

    gemm_dl<128, 128, 0><<<dim3(N_QKV / 128, M_TOT / 128), 256, 0, stream>>>(
        xb, WqT, bqkv, M_TOT, N_QKV, D_, qb, kb, vtb, nullptr);

    attn<<<dim3(B_ * H_, T_ / 256), 512, 0, stream>>>(qb, kb, vtb, aob);

    gemm_dl<128, 64, 1><<<dim3(D_ / 64, M_TOT / 128), 256, 0, stream>>>(
        aob, WoT, bout, M_TOT, D_, D_, nullptr, nullptr, nullptr, out);
}

// Round 23
// 124.825 us; speedup vs baseline: 1.0195x; 1.0195x over previous
//
#include <hip/hip_runtime.h>
#include <hip/hip_bf16.h>

#define B_   2
#define T_   2048
#define D_   1024
#define H_   16
#define HD_  64
#define M_TOT (B_*T_)    // 4096
#define N_QKV (3*D_)     // 3072

typedef __attribute__((ext_vector_type(8))) short bf16x8;
typedef __attribute__((ext_vector_type(4))) float f32x4;
typedef __attribute__((ext_vector_type(16))) float f32x16;

static __device__ __forceinline__ short f2bf(float f) {
    union { __hip_bfloat16 h; short s; } u;
    u.h = __float2bfloat16(f);
    return u.s;
}
static __device__ __forceinline__ unsigned pack2(float a, float b) {
    return (unsigned)(unsigned short)f2bf(a) | ((unsigned)(unsigned short)f2bf(b) << 16);
}
// HW packed f32->bf16 (RNE): D.lo16 = bf16(lo), D.hi16 = bf16(hi). 1 VALU op.
static __device__ __forceinline__ unsigned cvtpk(float lo, float hi) {
    unsigned r;
    asm("v_cvt_pk_bf16_f32 %0, %1, %2" : "=v"(r) : "v"(lo), "v"(hi));
    return r;
}
static __device__ __forceinline__ float exp2_fast(float x) {
    return __builtin_amdgcn_exp2f(x);
}
static __device__ __forceinline__ f32x16 zero16() {
    f32x16 z;
    #pragma unroll
    for (int i = 0; i < 16; ++i) z[i] = 0.f;
    return z;
}
// async global->LDS DMA, 16B per lane. LDS dest = wave-uniform base + lane*16.
static __device__ __forceinline__ void gload16(const void* g, void* l) {
    __builtin_amdgcn_global_load_lds(
        (__attribute__((address_space(1))) unsigned int*)(unsigned long long)g,
        (__attribute__((address_space(3))) unsigned int*)l, 16, 0, 0);
}
// NOTE (R9-R12): v_permlane32_swap_b32 failed the 2x2 factorial; PV exchange
// stays on __shfl_xor (verified). NOTE (R14): counted-vmcnt in attn neutral.
// NOTE (R16): T15 att[2] pipeline regressed. NOTE (R17): depth-2 GEMM
// prefetch neutral (kept). NOTE (R18/R19): KV split-K net negative. NOTE
// (R20): bh-grouped grid cut attn FETCH 69.7->12.3MB (kept). NOTE (R21):
// HW cvt_pk P-pack -3us (kept). NOTE (R22): setprio around MFMA clusters
// REGRESSED attn 58->60 (waves are near-lockstep between barriers) -- revert.
// R23: KVBLK=128 barrier window (2x 64-subtiles per __syncthreads, 4 LDS
// sub-buffers in 64KB) halves barrier count 32->16; epilogue cvtpk.

// ---------------------------------------------------------------------------
// x fp32 -> bf16, straight copy (8 elems/thread)
__global__ __launch_bounds__(256) void convert_x(const float* __restrict__ x,
                                                 short* __restrict__ xb, int n8) {
    int i = blockIdx.x * blockDim.x + threadIdx.x;
    if (i >= n8) return;
    const float4* p = (const float4*)x + (size_t)i * 2;
    float4 a = p[0], b = p[1];
    bf16x8 o;
    o[0]=f2bf(a.x); o[1]=f2bf(a.y); o[2]=f2bf(a.z); o[3]=f2bf(a.w);
    o[4]=f2bf(b.x); o[5]=f2bf(b.y); o[6]=f2bf(b.z); o[7]=f2bf(b.w);
    *((bf16x8*)xb + i) = o;
}

// in [K][N] fp32  ->  out [N][K] bf16 (B^T layout for GEMM), 64x64 LDS tiles
__global__ __launch_bounds__(256) void transpose_convert(const float* __restrict__ in,
                                                         short* __restrict__ out,
                                                         int K, int N) {
    __shared__ short tile[64][65];
    int k0 = blockIdx.y * 64, n0 = blockIdx.x * 64;
    int t = threadIdx.x;
    #pragma unroll
    for (int i = 0; i < 16; ++i) {
        int idx = i * 256 + t;
        int r = idx >> 6, c = idx & 63;
        tile[r][c] = f2bf(in[(size_t)(k0 + r) * N + n0 + c]);
    }
    __syncthreads();
    #pragma unroll
    for (int i = 0; i < 16; ++i) {
        int idx = i * 256 + t;
        int r = idx >> 6, c = idx & 63;     // r: n-local, c: k-local
        out[(size_t)(n0 + r) * K + k0 + c] = tile[c][r];
    }
}

// ---------------------------------------------------------------------------
// BK=32 GEMM with depth-2 prefetch (R17-verified). C = A*BT^T + bias.
#define QSC 0.18033688f   // 0.125 * log2(e)
template<int BM, int BN, int MODE>
__global__ __launch_bounds__(256)
void gemm_dl(const short* __restrict__ A, const short* __restrict__ BT,
             const float* __restrict__ bias, int M, int N, int K,
             short* __restrict__ qo, short* __restrict__ ko,
             short* __restrict__ vo, float* __restrict__ fo) {
    constexpr int BUF = (BM + BN) * 64;        // bytes per stage buffer (64B rows)
    constexpr int NL = (BM + BN) / 64;         // DMA instrs per thread per stage
    __shared__ char smem[3 * BUF];
    const int t = threadIdx.x, w = t >> 6, l = t & 63;
    const int qi_l = l & 15, hi_l = l >> 4;
    const int m0 = blockIdx.y * BM, n0 = blockIdx.x * BN;
    const int wr = w >> 1, wc = w & 1;
    constexpr int MI = BM / 32, NI = BN / 32;

    f32x4 acc[MI][NI];
    #pragma unroll
    for (int mi = 0; mi < MI; ++mi)
        #pragma unroll
        for (int ni = 0; ni < NI; ++ni)
            acc[mi][ni] = (f32x4){0.f, 0.f, 0.f, 0.f};

    const int lrow = l >> 2;                     // 0..15 rows within one 1KB DMA
    const int lch  = ((l & 3) ^ (lrow & 3)) * 8; // pre-swizzled source chunk (elems)

    auto stage = [&](char* dst, int k0) {
        #pragma unroll
        for (int i = 0; i < BM / 64; ++i) {
            int rb = w * (BM / 4) + i * 16;
            gload16(A + (size_t)(m0 + rb + lrow) * K + k0 + lch, dst + rb * 64);
        }
        #pragma unroll
        for (int i = 0; i < BN / 64; ++i) {
            int rb = w * (BN / 4) + i * 16;
            gload16(BT + (size_t)(n0 + rb + lrow) * K + k0 + lch, dst + BM * 64 + rb * 64);
        }
    };

    const int nt = K / 32;
    stage(smem, 0);
    if (nt > 1) stage(smem + BUF, 32);
    for (int it = 0; it < nt; ++it) {
        if (it + 2 < nt) {
            stage(smem + ((it + 2) % 3) * BUF, (it + 2) * 32);  // t+2 in flight
            if constexpr (NL == 4)      asm volatile("s_waitcnt vmcnt(8)" ::: "memory");
            else if constexpr (NL == 3) asm volatile("s_waitcnt vmcnt(6)" ::: "memory");
            else                        asm volatile("s_waitcnt vmcnt(0)" ::: "memory");
        } else if (it + 1 < nt) {
            if constexpr (NL == 4)      asm volatile("s_waitcnt vmcnt(4)" ::: "memory");
            else if constexpr (NL == 3) asm volatile("s_waitcnt vmcnt(3)" ::: "memory");
            else                        asm volatile("s_waitcnt vmcnt(0)" ::: "memory");
        } else {
            asm volatile("s_waitcnt vmcnt(0)" ::: "memory");
        }
        __builtin_amdgcn_s_barrier();    // B1: tile t visible to all waves

        char* sA = smem + (it % 3) * BUF;
        char* sB = sA + BM * 64;
        bf16x8 af[MI], bfr[NI];
        #pragma unroll
        for (int mi = 0; mi < MI; ++mi) {
            int row = wr * (BM / 2) + mi * 16 + qi_l;
            int ad = row * 64 + ((hi_l ^ (row & 3)) * 16);
            af[mi] = *(const bf16x8*)(sA + ad);
        }
        #pragma unroll
        for (int ni = 0; ni < NI; ++ni) {
            int row = wc * (BN / 2) + ni * 16 + qi_l;
            int ad = row * 64 + ((hi_l ^ (row & 3)) * 16);
            bfr[ni] = *(const bf16x8*)(sB + ad);
        }
        #pragma unroll
        for (int mi = 0; mi < MI; ++mi)
            #pragma unroll
            for (int ni = 0; ni < NI; ++ni)
                acc[mi][ni] = __builtin_amdgcn_mfma_f32_16x16x32_bf16(af[mi], bfr[ni], acc[mi][ni], 0, 0, 0);

        __builtin_amdgcn_s_barrier();    // B2: buf[it%3] reads done
    }

    #pragma unroll
    for (int mi = 0; mi < MI; ++mi) {
        int rbase = m0 + wr * (BM / 2) + mi * 16 + 4 * hi_l;
        #pragma unroll
        for (int ni = 0; ni < NI; ++ni) {
            int n = n0 + wc * (BN / 2) + ni * 16 + qi_l;
            float bv = bias[n];
            #pragma unroll
            for (int r = 0; r < 4; ++r) {
                int mm = rbase + r;
                float c = acc[mi][ni][r] + bv;
                if (MODE == 0) {
                    int which = n >> 10, rest = n & 1023;
                    int h = rest >> 6, d = rest & 63;
                    int b = mm >> 11, tq = mm & 2047;
                    size_t bh = (size_t)(b * H_ + h);
                    if (which == 0)      qo[(bh * T_ + tq) * HD_ + d] = f2bf(c * QSC);
                    else if (which == 1) ko[(bh * T_ + tq) * HD_ + d] = f2bf(c);
                    else                 vo[(bh * HD_ + d) * T_ + tq] = f2bf(c);
                } else {
                    fo[(size_t)mm * N + n] = c;
                }
            }
        }
    }
}

// ---------------------------------------------------------------------------
// Flash attention (R21-verified core: bh-major grid -> XCD=bh%8 L2 locality;
// 8 waves x 32 q-rows, swapped 32x32 MFMA, HW cvt_pk P-pack, NO setprio).
// R23: KVBLK=128 barrier window -- each __syncthreads covers TWO 64-kv
// subtiles (4 sub-buffers K0,K1,V0,V1 per half of 64KB LDS), halving
// barrier count 32->16. Per-subtile body identical to R21.
// q,k: [B*H, T, Hd] bf16 (q pre-scaled by 1/8*log2e); vt: [B*H, Hd, T] bf16.
__global__ __launch_bounds__(512)
void attn(const short* __restrict__ q, const short* __restrict__ k,
          const short* __restrict__ vt, short* __restrict__ ao) {
    // buf(cur) @ cur*32768: K0@0, K1@8192, V0@16384, V1@24576 (each 8KB)
    __shared__ char smem[65536];

    const int t = threadIdx.x, w = t >> 6, l = t & 63;
    const int q32 = l & 31, hi2 = l >> 5;
    const int swz = (l & 7) << 4;
    const int bh = blockIdx.x;                     // bh on x: XCD = bh % 8
    const int q0 = blockIdx.y * 256 + w * 32;      // q-tile on y

    const short* qptr = q + ((size_t)bh * T_ + q0) * HD_;
    const short* kbase = k + (size_t)bh * T_ * HD_;
    const short* vbase = vt + (size_t)bh * HD_ * T_;

    const int srow = w * 8 + (l >> 3);              // staging row (this wave: 8 rows)
    const int sch  = ((l & 7) ^ (l >> 3)) * 8;      // pre-swizzled source chunk

    // Q fragments: B-operand of 32x32x16: lane holds Q[q=q32][d = kc*16 + hi2*8 + j]
    bf16x8 qa[4];
    #pragma unroll
    for (int kc = 0; kc < 4; ++kc)
        qa[kc] = *(const bf16x8*)(qptr + q32 * HD_ + kc * 16 + hi2 * 8);

    f32x16 o0 = zero16(), o1 = zero16();
    float m = -1e30f, lsum = 0.f;

    // stage one 128-kv window (two 64-subtiles) into buf at dst
    auto stage = [&](int kb, char* dst) {
        gload16(kbase + (size_t)(kb + srow) * HD_ + sch,      dst + srow * 128);
        gload16(kbase + (size_t)(kb + 64 + srow) * HD_ + sch, dst + 8192 + srow * 128);
        gload16(vbase + (size_t)srow * T_ + kb + sch,         dst + 16384 + srow * 128);
        gload16(vbase + (size_t)srow * T_ + kb + 64 + sch,    dst + 24576 + srow * 128);
    };

    // one 64-kv subtile: QK -> online softmax -> PV (R21-verified body)
    auto subtile = [&](const char* sK, const char* sV) {
        f32x16 s0 = zero16(), s1 = zero16();
        #pragma unroll
        for (int kc = 0; kc < 4; ++kc) {
            int off = (kc * 32 + hi2 * 16) ^ swz;
            bf16x8 kf0 = *(const bf16x8*)(sK + q32 * 128 + off);
            s0 = __builtin_amdgcn_mfma_f32_32x32x16_bf16(kf0, qa[kc], s0, 0, 0, 0);
            bf16x8 kf1 = *(const bf16x8*)(sK + (32 + q32) * 128 + off);
            s1 = __builtin_amdgcn_mfma_f32_32x32x16_bf16(kf1, qa[kc], s1, 0, 0, 0);
        }

        float a8[8];
        #pragma unroll
        for (int i = 0; i < 8; ++i)
            a8[i] = fmaxf(fmaxf(s0[i], s0[i + 8]), fmaxf(s1[i], s1[i + 8]));
        float b4_0 = fmaxf(a8[0], a8[1]), b4_1 = fmaxf(a8[2], a8[3]);
        float b4_2 = fmaxf(a8[4], a8[5]), b4_3 = fmaxf(a8[6], a8[7]);
        float tm = fmaxf(fmaxf(b4_0, b4_1), fmaxf(b4_2, b4_3));
        tm = fmaxf(tm, __shfl_xor(tm, 32));

        if (!__all(tm <= m + 8.f)) {        // defer-max (T13)
            float mnew = fmaxf(m, tm);
            float fsc = exp2_fast(m - mnew);
            lsum *= fsc;
            #pragma unroll
            for (int i = 0; i < 16; ++i) { o0[i] *= fsc; o1[i] *= fsc; }
            m = mnew;
        }

        #pragma unroll
        for (int i = 0; i < 16; ++i) {
            s0[i] = exp2_fast(s0[i] - m);
            s1[i] = exp2_fast(s1[i] - m);
        }
        float p8[8];
        #pragma unroll
        for (int i = 0; i < 8; ++i)
            p8[i] = (s0[i] + s0[i + 8]) + (s1[i] + s1[i + 8]);
        float psum = ((p8[0] + p8[1]) + (p8[2] + p8[3])) + ((p8[4] + p8[5]) + (p8[6] + p8[7]));
        psum += __shfl_xor(psum, 32);
        lsum += psum;

        unsigned pk0[8], pk1[8];
        #pragma unroll
        for (int p = 0; p < 8; ++p) {
            pk0[p] = cvtpk(s0[2 * p], s0[2 * p + 1]);
            pk1[p] = cvtpk(s1[2 * p], s1[2 * p + 1]);
        }

        #pragma unroll
        for (int c = 0; c < 4; ++c) {
            unsigned w0 = (c & 2) ? pk1[(c & 1) * 4 + 0] : pk0[(c & 1) * 4 + 0];
            unsigned w1 = (c & 2) ? pk1[(c & 1) * 4 + 1] : pk0[(c & 1) * 4 + 1];
            unsigned w2 = (c & 2) ? pk1[(c & 1) * 4 + 2] : pk0[(c & 1) * 4 + 2];
            unsigned w3 = (c & 2) ? pk1[(c & 1) * 4 + 3] : pk0[(c & 1) * 4 + 3];
            unsigned t0 = hi2 ? w0 : w2;
            unsigned t1 = hi2 ? w1 : w3;
            unsigned r0 = __shfl_xor(t0, 32);
            unsigned r1 = __shfl_xor(t1, 32);
            union { unsigned u[4]; bf16x8 v; } uf;
            uf.u[0] = hi2 ? r0 : w0;
            uf.u[1] = hi2 ? r1 : w1;
            uf.u[2] = hi2 ? w2 : r0;
            uf.u[3] = hi2 ? w3 : r1;
            bf16x8 pf = uf.v;

            int off = (c * 32 + hi2 * 16) ^ swz;
            bf16x8 vf0 = *(const bf16x8*)(sV + q32 * 128 + off);
            o0 = __builtin_amdgcn_mfma_f32_32x32x16_bf16(vf0, pf, o0, 0, 0, 0);
            bf16x8 vf1 = *(const bf16x8*)(sV + (32 + q32) * 128 + off);
            o1 = __builtin_amdgcn_mfma_f32_32x32x16_bf16(vf1, pf, o1, 0, 0, 0);
        }
    };

    // prologue: stage window 0 into buf 0
    stage(0, smem);
    __syncthreads();

    int cur = 0;
    for (int kb = 0; kb < T_; kb += 128) {
        char* base = smem + cur * 32768;
        if (kb + 128 < T_) stage(kb + 128, smem + (cur ^ 1) * 32768);

        subtile(base, base + 16384);            // kv [kb, kb+64)
        subtile(base + 8192, base + 24576);     // kv [kb+64, kb+128)

        __syncthreads();    // DMA drained + all waves done with buf[cur]
        cur ^= 1;
    }

    const float inv = 1.f / lsum;
    const int b = bh >> 4, h = bh & 15;
    const int tq = q0 + q32;
    unsigned* aou = (unsigned*)(ao + ((size_t)(b * T_ + tq)) * D_ + h * HD_);
    #pragma unroll
    for (int pr = 0; pr < 8; ++pr) {
        int d0 = 2 * (pr & 1) + 8 * (pr >> 1) + 4 * hi2;    // even
        aou[d0 >> 1]        = cvtpk(o0[2 * pr] * inv, o0[2 * pr + 1] * inv);
        aou[(32 + d0) >> 1] = cvtpk(o1[2 * pr] * inv, o1[2 * pr + 1] * inv);
    }
}

// ---------------------------------------------------------------------------
extern "C" void kernel_launch(void* const* d_in, const int* in_sizes, int n_in,
                              void* d_out, int out_size, void* d_ws, size_t ws_size,
                              hipStream_t stream) {
    const float* x    = (const float*)d_in[0];
    const float* Wqkv = (const float*)d_in[1];
    const float* bqkv = (const float*)d_in[2];
    const float* Wout = (const float*)d_in[3];
    const float* bout = (const float*)d_in[4];
    float* out = (float*)d_out;

    char* ws = (char*)d_ws;
    short* xb  = (short*)(ws);                      // 8 MB  x bf16 [4096][1024]
    short* WqT = (short*)(ws + ((size_t)8  << 20)); // 6 MB  Wqkv^T bf16 [3072][1024]
    short* WoT = (short*)(ws + ((size_t)14 << 20)); // 2 MB  Wout^T bf16 [1024][1024]
    short* qb  = (short*)(ws + ((size_t)16 << 20)); // 8 MB  q [B*H][T][Hd]
    short* kb  = (short*)(ws + ((size_t)24 << 20)); // 8 MB  k [B*H][T][Hd]
    short* vtb = (short*)(ws + ((size_t)32 << 20)); // 8 MB  v^T [B*H][Hd][T]
    short* aob = (short*)(ws + ((size_t)40 << 20)); // 8 MB  attn out bf16 [4096][1024]

    convert_x<<<(M_TOT * D_ / 8 + 255) / 256, 256, 0, stream>>>(x, xb, M_TOT * D_ / 8);
    transpose_convert<<<dim3(N_QKV / 64, D_ / 64), 256, 0, stream>>>(Wqkv, WqT, D_, N_QKV);
    transpose_convert<<<dim3(D_ / 64, D_ / 64), 256, 0, stream>>>(Wout, WoT, D_, D_);

    gemm_dl<128, 128, 0><<<dim3(N_QKV / 128, M_TOT / 128), 256, 0, stream>>>(
        xb, WqT, bqkv, M_TOT, N_QKV, D_, qb, kb, vtb, nullptr);

    attn<<<dim3(B_ * H_, T_ / 256), 512, 0, stream>>>(qb, kb, vtb, aob);

    gemm_dl<128, 64, 1><<<dim3(D_ / 64, M_TOT / 128), 256, 0, stream>>>(
        aob, WoT, bout, M_TOT, D_, D_, nullptr, nullptr, nullptr, out);
}